// Round 2
// baseline (3180.442 us; speedup 1.0000x reference)
//
#include <hip/hip_runtime.h>
#include <hip/hip_fp16.h>
#include <stdint.h>

#define NUM_IT 64
#define BATCH 64
#define HW 50176            // 224*224
#define CHW 150528          // 3*HW
#define NELEM 9633792       // 64*CHW
#define SIGMA 0.05f

// ws layout: dots[(NUM_IT+1)*BATCH] | coef[BATCH*NUM_IT] | ts[NUM_IT*BATCH*HW] half2
#define WS_FLOATS ((NUM_IT + 1) * BATCH + BATCH * NUM_IT)
#define TS_PAIRS  ((size_t)NUM_IT * BATCH * HW)               // 205,520,896
#define WS_NEEDED ((size_t)WS_FLOATS * 4 + TS_PAIRS * 4)      // ~822 MB

// ---------------- Threefry-2x32, 20 rounds (JAX-exact) ----------------
__device__ __forceinline__ void tf2x32(uint32_t k0, uint32_t k1,
                                       uint32_t x0, uint32_t x1,
                                       uint32_t &o0, uint32_t &o1) {
  const uint32_t ks2 = k0 ^ k1 ^ 0x1BD11BDAu;
  x0 += k0; x1 += k1;
#define TF_R(r) { x0 += x1; x1 = __builtin_amdgcn_alignbit(x1, x1, 32u - (r)); x1 ^= x0; }
  TF_R(13) TF_R(15) TF_R(26) TF_R(6)
  x0 += k1;  x1 += ks2 + 1u;
  TF_R(17) TF_R(29) TF_R(16) TF_R(24)
  x0 += ks2; x1 += k0 + 2u;
  TF_R(13) TF_R(15) TF_R(26) TF_R(6)
  x0 += k0;  x1 += k1 + 3u;
  TF_R(17) TF_R(29) TF_R(16) TF_R(24)
  x0 += k1;  x1 += ks2 + 4u;
  TF_R(13) TF_R(15) TF_R(26) TF_R(6)
  x0 += ks2; x1 += k0 + 5u;
#undef TF_R
  o0 = x0; o1 = x1;
}

// bits -> uniform(-0.99999994, 1) -> sqrt(2)*erfinv (XLA/Giles f32 poly)
__device__ __forceinline__ float bits_to_normal(uint32_t bits) {
  const float LO = __uint_as_float(0xBF7FFFFFu);     // nextafter(-1,0)
  float u01 = __uint_as_float((bits >> 9) | 0x3f800000u) - 1.0f;  // [0,1)
  float u = fmaf(u01, 2.0f, LO);
  u = fmaxf(u, LO);
  // 1 - round(u*u) is Sterbenz-exact; __fmul_rn blocks fp-contraction.
  float s = __fmul_rn(u, u);
  float w = -__logf(1.0f - s);
  float p;
  if (w < 5.0f) {
    float z = w - 2.5f;
    p = 2.81022636e-08f;
    p = fmaf(p, z, 3.43273939e-07f);
    p = fmaf(p, z, -3.5233877e-06f);
    p = fmaf(p, z, -4.39150654e-06f);
    p = fmaf(p, z, 0.00021858087f);
    p = fmaf(p, z, -0.00125372503f);
    p = fmaf(p, z, -0.00417768164f);
    p = fmaf(p, z, 0.246640727f);
    p = fmaf(p, z, 1.50140941f);
  } else {
    float z = sqrtf(w) - 3.0f;
    p = -0.000200214257f;
    p = fmaf(p, z, 0.000100950558f);
    p = fmaf(p, z, 0.00134934322f);
    p = fmaf(p, z, -0.00367342844f);
    p = fmaf(p, z, 0.00573950773f);
    p = fmaf(p, z, -0.0076224613f);
    p = fmaf(p, z, 0.00943887047f);
    p = fmaf(p, z, 1.00167406f);
    p = fmaf(p, z, 2.83297682f);
  }
  return 1.41421356237309515f * (p * u);
}

__global__ __launch_bounds__(256) void prep_kernel(const float4* __restrict__ imgs,
                                                   const float4* __restrict__ noise,
                                                   float4* __restrict__ base,
                                                   float* __restrict__ dots) {
  int gid = blockIdx.x * 256 + threadIdx.x;          // NELEM/4 blocks*threads exactly
  float4 a = imgs[gid], b = noise[gid];
  float4 r;
  r.x = a.x + b.x; r.y = a.y + b.y; r.z = a.z + b.z; r.w = a.w + b.w;
  base[gid] = r;
  if (gid < (NUM_IT + 1) * BATCH) dots[gid] = 0.0f;
}

// Pass 1: per (ii, b): logit = dot(clip(base + t_ii), w). ii==NUM_IT is prob2.
// STORE: also stash scaled deviations (t0,t1) as half2 for pass2 (t2 = -(t0+t1)).
template <bool STORE>
__global__ __launch_bounds__(256) void pass1_kernel(const float* __restrict__ base,
                                                    const float* __restrict__ wv,
                                                    float* __restrict__ dots,
                                                    __half2* __restrict__ ts) {
  const int chunk = blockIdx.x;   // 0..48
  const int b     = blockIdx.y;   // 0..63
  const int ii    = blockIdx.z;   // 0..64
  uint32_t kx = 0u, ky = 0u;
  if (ii < NUM_IT) tf2x32(0u, 42u, 0u, (uint32_t)ii, kx, ky);

  const int hw0 = chunk * 1024 + threadIdx.x;
  const int eb  = b * CHW;
  float sum = 0.0f;
#pragma unroll
  for (int s = 0; s < 4; ++s) {
    const int hw = hw0 + s * 256;
    float b0 = base[eb + hw];
    float b1 = base[eb + HW + hw];
    float b2 = base[eb + 2 * HW + hw];
    float w0 = wv[hw], w1 = wv[HW + hw], w2 = wv[2 * HW + hw];
    float a0 = b0, a1 = b1, a2 = b2;
    if (ii < NUM_IT) {
      uint32_t o0, o1;
      const uint32_t e = (uint32_t)(eb + hw);
      tf2x32(kx, ky, 0u, e,            o0, o1); float t0 = bits_to_normal(o0 ^ o1);
      tf2x32(kx, ky, 0u, e + HW,       o0, o1); float t1 = bits_to_normal(o0 ^ o1);
      tf2x32(kx, ky, 0u, e + 2u * HW,  o0, o1); float t2 = bits_to_normal(o0 ^ o1);
      float mu = (t0 + t1 + t2) * (1.0f / 3.0f);
      float d0 = t0 - mu, d1 = t1 - mu, d2 = t2 - mu;
      float var = (d0 * d0 + d1 * d1 + d2 * d2) * 0.5f;   // ddof=1 over 3
      float sc = SIGMA / sqrtf(var);
      float s0 = d0 * sc, s1 = d1 * sc, s2 = d2 * sc;     // |si| <= SIGMA*sqrt(2)
      if (STORE)
        ts[(size_t)(ii * BATCH + b) * HW + hw] = __floats2half2_rn(s0, s1);
      a0 = b0 + s0; a1 = b1 + s1; a2 = b2 + s2;
    }
    a0 = fminf(fmaxf(a0, 0.0f), 1.0f);
    a1 = fminf(fmaxf(a1, 0.0f), 1.0f);
    a2 = fminf(fmaxf(a2, 0.0f), 1.0f);
    sum = fmaf(a0, w0, sum);
    sum = fmaf(a1, w1, sum);
    sum = fmaf(a2, w2, sum);
  }
  for (int off = 32; off > 0; off >>= 1) sum += __shfl_down(sum, off, 64);
  __shared__ float red[4];
  if ((threadIdx.x & 63) == 0) red[threadIdx.x >> 6] = sum;
  __syncthreads();
  if (threadIdx.x == 0)
    atomicAdd(&dots[ii * BATCH + b], red[0] + red[1] + red[2] + red[3]);
}

__global__ void coef_kernel(const float* __restrict__ dots,
                            const float* __restrict__ bptr,
                            float* __restrict__ coef) {
  const int b = threadIdx.x;  // 64 threads
  const float bias = bptr[0];
  const float p2 = 1.0f / (1.0f + expf(-(dots[NUM_IT * BATCH + b] + bias)));
  float nc = 0.0f;
  for (int i = 0; i < NUM_IT; ++i) {
    float ap = 1.0f / (1.0f + expf(-(dots[i * BATCH + b] + bias)));
    float d = p2 - ap;
    nc += d * d;
  }
  const float inv = 1.0f / ((float)NUM_IT * SIGMA * (sqrtf(nc) + 1e-10f));
  for (int i = 0; i < NUM_IT; ++i) {
    float ap = 1.0f / (1.0f + expf(-(dots[i * BATCH + b] + bias)));
    float d = p2 - ap;
    coef[b * NUM_IT + i] = d * inv;
  }
}

// Fast pass 2: stream staged half2 deviations; out = sum_i ts_i * coef[b][i].
__global__ __launch_bounds__(256) void pass2_fast_kernel(float* __restrict__ out,
                                                         const float* __restrict__ coef,
                                                         const __half2* __restrict__ ts) {
  __shared__ float cf[NUM_IT];
  const int b = blockIdx.y;
  if (threadIdx.x < NUM_IT) cf[threadIdx.x] = coef[b * NUM_IT + threadIdx.x];
  __syncthreads();
  const int hw0 = blockIdx.x * 1024 + threadIdx.x;
  float acc[4][2];
#pragma unroll
  for (int s = 0; s < 4; ++s) { acc[s][0] = 0.f; acc[s][1] = 0.f; }

#pragma unroll 1
  for (int i = 0; i < NUM_IT; ++i) {
    const float ci = cf[i];
    const __half2* row = ts + (size_t)(i * BATCH + b) * HW;
#pragma unroll
    for (int s = 0; s < 4; ++s) {
      float2 v = __half22float2(row[hw0 + s * 256]);
      acc[s][0] = fmaf(v.x, ci, acc[s][0]);
      acc[s][1] = fmaf(v.y, ci, acc[s][1]);
    }
  }
  const int eb = b * CHW;
#pragma unroll
  for (int s = 0; s < 4; ++s) {
    const int hw = hw0 + s * 256;
    out[eb + hw]          = acc[s][0];
    out[eb + HW + hw]     = acc[s][1];
    out[eb + 2 * HW + hw] = -(acc[s][0] + acc[s][1]);   // t2 = -(t0+t1) exactly
  }
}

// Fallback pass 2 (regenerate) when ws is too small for staging.
__global__ __launch_bounds__(256) void pass2_regen_kernel(float* __restrict__ out,
                                                          const float* __restrict__ coef) {
  __shared__ float cf[NUM_IT];
  __shared__ uint32_t kxs[NUM_IT], kys[NUM_IT];
  const int b = blockIdx.y;
  if (threadIdx.x < NUM_IT) {
    uint32_t kx, ky;
    tf2x32(0u, 42u, 0u, (uint32_t)threadIdx.x, kx, ky);
    kxs[threadIdx.x] = kx; kys[threadIdx.x] = ky;
    cf[threadIdx.x] = coef[b * NUM_IT + threadIdx.x];
  }
  __syncthreads();
  const int hw0 = blockIdx.x * 1024 + threadIdx.x;
  const int eb  = b * CHW;
  float acc[4][3];
#pragma unroll
  for (int s = 0; s < 4; ++s) { acc[s][0] = 0.f; acc[s][1] = 0.f; acc[s][2] = 0.f; }
#pragma unroll 1
  for (int i = 0; i < NUM_IT; ++i) {
    const uint32_t kx = kxs[i], ky = kys[i];
    const float ci = cf[i];
#pragma unroll
    for (int s = 0; s < 4; ++s) {
      const uint32_t e = (uint32_t)(eb + hw0 + s * 256);
      uint32_t o0, o1;
      tf2x32(kx, ky, 0u, e,           o0, o1); float t0 = bits_to_normal(o0 ^ o1);
      tf2x32(kx, ky, 0u, e + HW,      o0, o1); float t1 = bits_to_normal(o0 ^ o1);
      tf2x32(kx, ky, 0u, e + 2u * HW, o0, o1); float t2 = bits_to_normal(o0 ^ o1);
      float mu = (t0 + t1 + t2) * (1.0f / 3.0f);
      float d0 = t0 - mu, d1 = t1 - mu, d2 = t2 - mu;
      float var = (d0 * d0 + d1 * d1 + d2 * d2) * 0.5f;
      float g = (SIGMA / sqrtf(var)) * ci;
      acc[s][0] = fmaf(d0, g, acc[s][0]);
      acc[s][1] = fmaf(d1, g, acc[s][1]);
      acc[s][2] = fmaf(d2, g, acc[s][2]);
    }
  }
#pragma unroll
  for (int s = 0; s < 4; ++s) {
    const int hw = hw0 + s * 256;
    out[eb + hw]          = acc[s][0];
    out[eb + HW + hw]     = acc[s][1];
    out[eb + 2 * HW + hw] = acc[s][2];
  }
}

extern "C" void kernel_launch(void* const* d_in, const int* in_sizes, int n_in,
                              void* d_out, int out_size, void* d_ws, size_t ws_size,
                              hipStream_t stream) {
  const float* imgs  = (const float*)d_in[0];
  const float* noise = (const float*)d_in[1];
  const float* wv    = (const float*)d_in[2];
  const float* bptr  = (const float*)d_in[3];
  float* out  = (float*)d_out;
  float* dots = (float*)d_ws;
  float* coef = dots + (NUM_IT + 1) * BATCH;
  __half2* ts = (__half2*)(dots + WS_FLOATS);
  const bool fast = ws_size >= WS_NEEDED;   // constant across calls -> graph-safe

  prep_kernel<<<dim3(NELEM / 1024), dim3(256), 0, stream>>>(
      (const float4*)imgs, (const float4*)noise, (float4*)out, dots);
  if (fast) {
    pass1_kernel<true><<<dim3(49, BATCH, NUM_IT + 1), dim3(256), 0, stream>>>(out, wv, dots, ts);
    coef_kernel<<<dim3(1), dim3(64), 0, stream>>>(dots, bptr, coef);
    pass2_fast_kernel<<<dim3(49, BATCH), dim3(256), 0, stream>>>(out, coef, ts);
  } else {
    pass1_kernel<false><<<dim3(49, BATCH, NUM_IT + 1), dim3(256), 0, stream>>>(out, wv, dots, ts);
    coef_kernel<<<dim3(1), dim3(64), 0, stream>>>(dots, bptr, coef);
    pass2_regen_kernel<<<dim3(49, BATCH), dim3(256), 0, stream>>>(out, coef);
  }
}

// Round 3
// 2742.554 us; speedup vs baseline: 1.1597x; 1.1597x over previous
//
#include <hip/hip_runtime.h>
#include <hip/hip_fp16.h>
#include <stdint.h>

#define NUM_IT 64
#define BATCH 64
#define HW 50176            // 224*224
#define CHW 150528          // 3*HW
#define SIGMA 0.05f

// ws layout: dots[(NUM_IT+1)*BATCH] | coef[BATCH*NUM_IT] | ts[k*BATCH*HW] half2
#define WS_FLOATS ((NUM_IT + 1) * BATCH + BATCH * NUM_IT)   // 8256 floats

// ---------------- Threefry-2x32, 20 rounds (JAX-exact) ----------------
__device__ __forceinline__ void tf2x32(uint32_t k0, uint32_t k1,
                                       uint32_t x0, uint32_t x1,
                                       uint32_t &o0, uint32_t &o1) {
  const uint32_t ks2 = k0 ^ k1 ^ 0x1BD11BDAu;
  x0 += k0; x1 += k1;
#define TF_R(r) { x0 += x1; x1 = __builtin_amdgcn_alignbit(x1, x1, 32u - (r)); x1 ^= x0; }
  TF_R(13) TF_R(15) TF_R(26) TF_R(6)
  x0 += k1;  x1 += ks2 + 1u;
  TF_R(17) TF_R(29) TF_R(16) TF_R(24)
  x0 += ks2; x1 += k0 + 2u;
  TF_R(13) TF_R(15) TF_R(26) TF_R(6)
  x0 += k0;  x1 += k1 + 3u;
  TF_R(17) TF_R(29) TF_R(16) TF_R(24)
  x0 += k1;  x1 += ks2 + 4u;
  TF_R(13) TF_R(15) TF_R(26) TF_R(6)
  x0 += ks2; x1 += k0 + 5u;
#undef TF_R
  o0 = x0; o1 = x1;
}

// bits -> uniform(-0.99999994, 1) -> sqrt(2)*erfinv (XLA/Giles f32 poly).
// scale (1-lo) rounds to exactly 2.0f (tie-to-even), and 2*u01 is exact, so
// fma == mul+add here; RN monotonicity makes the max(lo,·) a no-op.
__device__ __forceinline__ float bits_to_normal(uint32_t bits) {
  const float LO = __uint_as_float(0xBF7FFFFFu);     // nextafter(-1,0)
  float u01 = __uint_as_float((bits >> 9) | 0x3f800000u) - 1.0f;  // [0,1)
  float u = fmaf(u01, 2.0f, LO);
  // 1 - round(u*u) is Sterbenz-exact; __fmul_rn blocks fp-contraction.
  float s = __fmul_rn(u, u);
  float w = -__logf(1.0f - s);
  float p;
  if (w < 5.0f) {
    float z = w - 2.5f;
    p = 2.81022636e-08f;
    p = fmaf(p, z, 3.43273939e-07f);
    p = fmaf(p, z, -3.5233877e-06f);
    p = fmaf(p, z, -4.39150654e-06f);
    p = fmaf(p, z, 0.00021858087f);
    p = fmaf(p, z, -0.00125372503f);
    p = fmaf(p, z, -0.00417768164f);
    p = fmaf(p, z, 0.246640727f);
    p = fmaf(p, z, 1.50140941f);
  } else {
    float z = sqrtf(w) - 3.0f;
    p = -0.000200214257f;
    p = fmaf(p, z, 0.000100950558f);
    p = fmaf(p, z, 0.00134934322f);
    p = fmaf(p, z, -0.00367342844f);
    p = fmaf(p, z, 0.00573950773f);
    p = fmaf(p, z, -0.0076224613f);
    p = fmaf(p, z, 0.00943887047f);
    p = fmaf(p, z, 1.00167406f);
    p = fmaf(p, z, 2.83297682f);
  }
  return 1.41421356237309515f * (p * u);
}

__device__ __forceinline__ float clip01(float x) {
  return fminf(fmaxf(x, 0.0f), 1.0f);
}

// Pass 1: one block per (chunk,b). base+w live in registers across all 65
// ii-iterations; wave-level reduce + atomic (no barrier in hot loop).
__global__ __launch_bounds__(256) void pass1_kernel(
    const float* __restrict__ imgs, const float* __restrict__ noise,
    const float* __restrict__ wv, float* __restrict__ dots,
    __half2* __restrict__ ts, const int k)
{
  __shared__ uint32_t kxs[NUM_IT], kys[NUM_IT];
  if (threadIdx.x < NUM_IT) {
    uint32_t kx, ky;
    tf2x32(0u, 42u, 0u, (uint32_t)threadIdx.x, kx, ky);
    kxs[threadIdx.x] = kx; kys[threadIdx.x] = ky;
  }
  __syncthreads();

  const int b    = blockIdx.y;
  const int hw   = blockIdx.x * 1024 + threadIdx.x * 4;   // 4 contiguous elems
  const int ebhw = b * CHW + hw;

  float ba[3][4], wc[3][4];
#pragma unroll
  for (int ch = 0; ch < 3; ++ch) {
    float4 iv = *(const float4*)(imgs  + ebhw + ch * HW);
    float4 nv = *(const float4*)(noise + ebhw + ch * HW);
    float4 wvv = *(const float4*)(wv   + hw   + ch * HW);
    ba[ch][0] = iv.x + nv.x; ba[ch][1] = iv.y + nv.y;
    ba[ch][2] = iv.z + nv.z; ba[ch][3] = iv.w + nv.w;
    wc[ch][0] = wvv.x; wc[ch][1] = wvv.y; wc[ch][2] = wvv.z; wc[ch][3] = wvv.w;
  }

  // prob2 lane: dot of clip(base)
  {
    float sum = 0.0f;
#pragma unroll
    for (int ch = 0; ch < 3; ++ch)
#pragma unroll
      for (int j = 0; j < 4; ++j)
        sum = fmaf(clip01(ba[ch][j]), wc[ch][j], sum);
    for (int off = 32; off; off >>= 1) sum += __shfl_down(sum, off, 64);
    if ((threadIdx.x & 63) == 0) atomicAdd(&dots[NUM_IT * BATCH + b], sum);
  }

#pragma unroll 1
  for (int ii = 0; ii < NUM_IT; ++ii) {
    const uint32_t kx = kxs[ii], ky = kys[ii];
    float sum = 0.0f;
    union { __half2 h[4]; float4 f; } st;
#pragma unroll
    for (int j = 0; j < 4; ++j) {
      const uint32_t e = (uint32_t)(ebhw + j);
      uint32_t o0, o1;
      tf2x32(kx, ky, 0u, e,           o0, o1); float t0 = bits_to_normal(o0 ^ o1);
      tf2x32(kx, ky, 0u, e + HW,      o0, o1); float t1 = bits_to_normal(o0 ^ o1);
      tf2x32(kx, ky, 0u, e + 2u * HW, o0, o1); float t2 = bits_to_normal(o0 ^ o1);
      float mu = (t0 + t1 + t2) * (1.0f / 3.0f);
      float d0 = t0 - mu, d1 = t1 - mu, d2 = t2 - mu;
      float var = (d0 * d0 + d1 * d1 + d2 * d2) * 0.5f;   // ddof=1 over 3
      float sc = SIGMA / sqrtf(var);
      float s0 = d0 * sc, s1 = d1 * sc, s2 = d2 * sc;     // |si| <= sigma*sqrt(2)
      st.h[j] = __floats2half2_rn(s0, s1);
      sum = fmaf(clip01(ba[0][j] + s0), wc[0][j], sum);
      sum = fmaf(clip01(ba[1][j] + s1), wc[1][j], sum);
      sum = fmaf(clip01(ba[2][j] + s2), wc[2][j], sum);
    }
    if (ii < k)
      *(float4*)(ts + (size_t)(ii * BATCH + b) * HW + hw) = st.f;
    for (int off = 32; off; off >>= 1) sum += __shfl_down(sum, off, 64);
    if ((threadIdx.x & 63) == 0) atomicAdd(&dots[ii * BATCH + b], sum);
  }
}

__global__ void coef_kernel(const float* __restrict__ dots,
                            const float* __restrict__ bptr,
                            float* __restrict__ coef) {
  const int b = threadIdx.x;  // 64 threads
  const float bias = bptr[0];
  const float p2 = 1.0f / (1.0f + expf(-(dots[NUM_IT * BATCH + b] + bias)));
  float nc = 0.0f;
  for (int i = 0; i < NUM_IT; ++i) {
    float ap = 1.0f / (1.0f + expf(-(dots[i * BATCH + b] + bias)));
    float d = p2 - ap;
    nc += d * d;
  }
  const float inv = 1.0f / ((float)NUM_IT * SIGMA * (sqrtf(nc) + 1e-10f));
  for (int i = 0; i < NUM_IT; ++i) {
    float ap = 1.0f / (1.0f + expf(-(dots[i * BATCH + b] + bias)));
    float d = p2 - ap;
    coef[b * NUM_IT + i] = d * inv;
  }
}

// Pass 2: i<k streams staged half2 pairs; i>=k regenerates. ch2 derived as
// -(ch0+ch1): exact for staged, ~1e-7 off for regen (d0+d1+d2 ~ ulp) — within budget.
__global__ __launch_bounds__(256) void pass2_kernel(
    float* __restrict__ out, const float* __restrict__ coef,
    const __half2* __restrict__ ts, const int k)
{
  __shared__ float cf[NUM_IT];
  __shared__ uint32_t kxs[NUM_IT], kys[NUM_IT];
  const int b = blockIdx.y;
  if (threadIdx.x < NUM_IT) {
    uint32_t kx, ky;
    tf2x32(0u, 42u, 0u, (uint32_t)threadIdx.x, kx, ky);
    kxs[threadIdx.x] = kx; kys[threadIdx.x] = ky;
    cf[threadIdx.x] = coef[b * NUM_IT + threadIdx.x];
  }
  __syncthreads();

  const int hw   = blockIdx.x * 1024 + threadIdx.x * 4;
  const int ebhw = b * CHW + hw;
  float acc0[4] = {0.f, 0.f, 0.f, 0.f};
  float acc1[4] = {0.f, 0.f, 0.f, 0.f};

#pragma unroll 1
  for (int i = 0; i < NUM_IT; ++i) {
    const float ci = cf[i];
    if (i < k) {
      union { float4 f; __half2 h[4]; } u;
      u.f = *(const float4*)(ts + (size_t)(i * BATCH + b) * HW + hw);
#pragma unroll
      for (int j = 0; j < 4; ++j) {
        float2 v = __half22float2(u.h[j]);
        acc0[j] = fmaf(v.x, ci, acc0[j]);
        acc1[j] = fmaf(v.y, ci, acc1[j]);
      }
    } else {
      const uint32_t kx = kxs[i], ky = kys[i];
#pragma unroll
      for (int j = 0; j < 4; ++j) {
        const uint32_t e = (uint32_t)(ebhw + j);
        uint32_t o0, o1;
        tf2x32(kx, ky, 0u, e,           o0, o1); float t0 = bits_to_normal(o0 ^ o1);
        tf2x32(kx, ky, 0u, e + HW,      o0, o1); float t1 = bits_to_normal(o0 ^ o1);
        tf2x32(kx, ky, 0u, e + 2u * HW, o0, o1); float t2 = bits_to_normal(o0 ^ o1);
        float mu = (t0 + t1 + t2) * (1.0f / 3.0f);
        float d0 = t0 - mu, d1 = t1 - mu, d2 = t2 - mu;
        float var = (d0 * d0 + d1 * d1 + d2 * d2) * 0.5f;
        float g = (SIGMA / sqrtf(var)) * ci;
        acc0[j] = fmaf(d0, g, acc0[j]);
        acc1[j] = fmaf(d1, g, acc1[j]);
      }
    }
  }
  float4 v0, v1, v2;
  v0.x = acc0[0]; v0.y = acc0[1]; v0.z = acc0[2]; v0.w = acc0[3];
  v1.x = acc1[0]; v1.y = acc1[1]; v1.z = acc1[2]; v1.w = acc1[3];
  v2.x = -(acc0[0] + acc1[0]); v2.y = -(acc0[1] + acc1[1]);
  v2.z = -(acc0[2] + acc1[2]); v2.w = -(acc0[3] + acc1[3]);
  *(float4*)(out + ebhw)          = v0;
  *(float4*)(out + ebhw + HW)     = v1;
  *(float4*)(out + ebhw + 2 * HW) = v2;
}

extern "C" void kernel_launch(void* const* d_in, const int* in_sizes, int n_in,
                              void* d_out, int out_size, void* d_ws, size_t ws_size,
                              hipStream_t stream) {
  const float* imgs  = (const float*)d_in[0];
  const float* noise = (const float*)d_in[1];
  const float* wv    = (const float*)d_in[2];
  const float* bptr  = (const float*)d_in[3];
  float* out  = (float*)d_out;
  float* dots = (float*)d_ws;
  float* coef = dots + (NUM_IT + 1) * BATCH;
  __half2* ts = (__half2*)(dots + WS_FLOATS);

  // Adaptive staging: stage as many iterations as ws allows (12.8 MB each).
  // ws_size is constant across calls -> same k every launch -> graph-safe.
  size_t avail = ws_size > (size_t)WS_FLOATS * 4 ? ws_size - (size_t)WS_FLOATS * 4 : 0;
  int k = (int)(avail / ((size_t)BATCH * HW * 4));
  if (k > NUM_IT) k = NUM_IT;

  hipMemsetAsync(dots, 0, (NUM_IT + 1) * BATCH * sizeof(float), stream);
  pass1_kernel<<<dim3(49, BATCH), dim3(256), 0, stream>>>(imgs, noise, wv, dots, ts, k);
  coef_kernel<<<dim3(1), dim3(64), 0, stream>>>(dots, bptr, coef);
  pass2_kernel<<<dim3(49, BATCH), dim3(256), 0, stream>>>(out, coef, ts, k);
}

// Round 4
// 2626.563 us; speedup vs baseline: 1.2109x; 1.0442x over previous
//
#include <hip/hip_runtime.h>
#include <hip/hip_fp16.h>
#include <stdint.h>

#define NUM_IT 64
#define BATCH 64
#define HW 50176            // 224*224
#define CHW 150528          // 3*HW
#define SIGMA 0.05f

// ws layout: dots[(NUM_IT+1)*BATCH] | coef[BATCH*NUM_IT] | ts[k*BATCH*HW] half2
#define WS_FLOATS ((NUM_IT + 1) * BATCH + BATCH * NUM_IT)   // 8256 floats

// ---------------- Threefry-2x32, 20 rounds (JAX-exact) ----------------
__device__ __forceinline__ void tf2x32(uint32_t k0, uint32_t k1,
                                       uint32_t x0, uint32_t x1,
                                       uint32_t &o0, uint32_t &o1) {
  const uint32_t ks2 = k0 ^ k1 ^ 0x1BD11BDAu;
  x0 += k0; x1 += k1;
#define TF_R(r) { x0 += x1; x1 = __builtin_amdgcn_alignbit(x1, x1, 32u - (r)); x1 ^= x0; }
  TF_R(13) TF_R(15) TF_R(26) TF_R(6)
  x0 += k1;  x1 += ks2 + 1u;
  TF_R(17) TF_R(29) TF_R(16) TF_R(24)
  x0 += ks2; x1 += k0 + 2u;
  TF_R(13) TF_R(15) TF_R(26) TF_R(6)
  x0 += k0;  x1 += k1 + 3u;
  TF_R(17) TF_R(29) TF_R(16) TF_R(24)
  x0 += k1;  x1 += ks2 + 4u;
  TF_R(13) TF_R(15) TF_R(26) TF_R(6)
  x0 += ks2; x1 += k0 + 5u;
#undef TF_R
  o0 = x0; o1 = x1;
}

// bits -> uniform(-0.99999994, 1) -> sqrt(2)*erfinv (XLA/Giles f32 poly).
__device__ __forceinline__ float bits_to_normal(uint32_t bits) {
  const float LO = __uint_as_float(0xBF7FFFFFu);     // nextafter(-1,0)
  float u01 = __uint_as_float((bits >> 9) | 0x3f800000u) - 1.0f;  // [0,1)
  float u = fmaf(u01, 2.0f, LO);
  // 1 - round(u*u) is Sterbenz-exact; __fmul_rn blocks fp-contraction.
  float s = __fmul_rn(u, u);
  float w = -__logf(1.0f - s);
  float p;
  if (w < 5.0f) {
    float z = w - 2.5f;
    p = 2.81022636e-08f;
    p = fmaf(p, z, 3.43273939e-07f);
    p = fmaf(p, z, -3.5233877e-06f);
    p = fmaf(p, z, -4.39150654e-06f);
    p = fmaf(p, z, 0.00021858087f);
    p = fmaf(p, z, -0.00125372503f);
    p = fmaf(p, z, -0.00417768164f);
    p = fmaf(p, z, 0.246640727f);
    p = fmaf(p, z, 1.50140941f);
  } else {
    float z = sqrtf(w) - 3.0f;
    p = -0.000200214257f;
    p = fmaf(p, z, 0.000100950558f);
    p = fmaf(p, z, 0.00134934322f);
    p = fmaf(p, z, -0.00367342844f);
    p = fmaf(p, z, 0.00573950773f);
    p = fmaf(p, z, -0.0076224613f);
    p = fmaf(p, z, 0.00943887047f);
    p = fmaf(p, z, 1.00167406f);
    p = fmaf(p, z, 2.83297682f);
  }
  return 1.41421356237309515f * (p * u);
}

__device__ __forceinline__ float clip01(float x) {
  return fminf(fmaxf(x, 0.0f), 1.0f);
}

// Pass 1: grid (49, BATCH, 13). Block z=g handles ii-units 5g..5g+4
// (unit 64 == prob2, in group 12). Fine tiles -> ~99% slot efficiency
// (R3's one-block-per-(chunk,b) had 76.6% cap, measured 54%).
__global__ __launch_bounds__(256) void pass1_kernel(
    const float* __restrict__ imgs, const float* __restrict__ noise,
    const float* __restrict__ wv, float* __restrict__ dots,
    __half2* __restrict__ ts, const int k)
{
  const int g = blockIdx.z;
  const int b = blockIdx.y;
  __shared__ uint32_t kxs[5], kys[5];
  if (threadIdx.x < 5) {
    const int u = 5 * g + threadIdx.x;
    if (u < NUM_IT) {
      uint32_t kx, ky;
      tf2x32(0u, 42u, 0u, (uint32_t)u, kx, ky);
      kxs[threadIdx.x] = kx; kys[threadIdx.x] = ky;
    }
  }
  __syncthreads();

  const int hw   = blockIdx.x * 1024 + threadIdx.x * 4;   // 4 contiguous elems
  const int ebhw = b * CHW + hw;

  float ba[3][4], wc[3][4];
#pragma unroll
  for (int ch = 0; ch < 3; ++ch) {
    float4 iv = *(const float4*)(imgs  + ebhw + ch * HW);
    float4 nv = *(const float4*)(noise + ebhw + ch * HW);
    float4 wvv = *(const float4*)(wv   + hw   + ch * HW);
    ba[ch][0] = iv.x + nv.x; ba[ch][1] = iv.y + nv.y;
    ba[ch][2] = iv.z + nv.z; ba[ch][3] = iv.w + nv.w;
    wc[ch][0] = wvv.x; wc[ch][1] = wvv.y; wc[ch][2] = wvv.z; wc[ch][3] = wvv.w;
  }

#pragma unroll 1
  for (int u = 0; u < 5; ++u) {
    const int unit = 5 * g + u;       // 0..64; 64 == prob2
    if (unit > NUM_IT) break;         // only possible past group 12's end
    const bool isP2 = (unit == NUM_IT);
    float sum = 0.0f;
    if (isP2) {
#pragma unroll
      for (int ch = 0; ch < 3; ++ch)
#pragma unroll
        for (int j = 0; j < 4; ++j)
          sum = fmaf(clip01(ba[ch][j]), wc[ch][j], sum);
    } else {
      const uint32_t kx = kxs[u], ky = kys[u];
      union { __half2 h[4]; float4 f; } st;
#pragma unroll
      for (int j = 0; j < 4; ++j) {
        const uint32_t e = (uint32_t)(ebhw + j);
        uint32_t o0, o1;
        tf2x32(kx, ky, 0u, e,           o0, o1); float t0 = bits_to_normal(o0 ^ o1);
        tf2x32(kx, ky, 0u, e + HW,      o0, o1); float t1 = bits_to_normal(o0 ^ o1);
        tf2x32(kx, ky, 0u, e + 2u * HW, o0, o1); float t2 = bits_to_normal(o0 ^ o1);
        float mu = (t0 + t1 + t2) * (1.0f / 3.0f);
        float d0 = t0 - mu, d1 = t1 - mu, d2 = t2 - mu;
        float var = (d0 * d0 + d1 * d1 + d2 * d2) * 0.5f;   // ddof=1 over 3
        float sc = SIGMA / sqrtf(var);
        float s0 = d0 * sc, s1 = d1 * sc, s2 = d2 * sc;     // |si| <= sigma*sqrt(2)
        st.h[j] = __floats2half2_rn(s0, s1);
        sum = fmaf(clip01(ba[0][j] + s0), wc[0][j], sum);
        sum = fmaf(clip01(ba[1][j] + s1), wc[1][j], sum);
        sum = fmaf(clip01(ba[2][j] + s2), wc[2][j], sum);
      }
      if (unit < k)
        *(float4*)(ts + (size_t)(unit * BATCH + b) * HW + hw) = st.f;
    }
    for (int off = 32; off; off >>= 1) sum += __shfl_down(sum, off, 64);
    if ((threadIdx.x & 63) == 0) atomicAdd(&dots[unit * BATCH + b], sum);
  }
}

__global__ void coef_kernel(const float* __restrict__ dots,
                            const float* __restrict__ bptr,
                            float* __restrict__ coef) {
  const int b = threadIdx.x;  // 64 threads
  const float bias = bptr[0];
  const float p2 = 1.0f / (1.0f + expf(-(dots[NUM_IT * BATCH + b] + bias)));
  float nc = 0.0f;
  for (int i = 0; i < NUM_IT; ++i) {
    float ap = 1.0f / (1.0f + expf(-(dots[i * BATCH + b] + bias)));
    float d = p2 - ap;
    nc += d * d;
  }
  const float inv = 1.0f / ((float)NUM_IT * SIGMA * (sqrtf(nc) + 1e-10f));
  for (int i = 0; i < NUM_IT; ++i) {
    float ap = 1.0f / (1.0f + expf(-(dots[i * BATCH + b] + bias)));
    float d = p2 - ap;
    coef[b * NUM_IT + i] = d * inv;
  }
}

// Pass 2: grid (49, BATCH, 4). Block z=ig handles i = 16*ig..16*ig+15;
// partials atomically added into zero-initialized out. i<k streams staged
// half2; i>=k regenerates. ch2 = -(ch0+ch1) (exact for staged; ~ulp for regen).
__global__ __launch_bounds__(256) void pass2_kernel(
    float* __restrict__ out, const float* __restrict__ coef,
    const __half2* __restrict__ ts, const int k)
{
  const int ig = blockIdx.z;
  const int b  = blockIdx.y;
  __shared__ float cf[16];
  __shared__ uint32_t kxs[16], kys[16];
  if (threadIdx.x < 16) {
    const int i = 16 * ig + threadIdx.x;
    cf[threadIdx.x] = coef[b * NUM_IT + i];
    if (i >= k) {
      uint32_t kx, ky;
      tf2x32(0u, 42u, 0u, (uint32_t)i, kx, ky);
      kxs[threadIdx.x] = kx; kys[threadIdx.x] = ky;
    }
  }
  __syncthreads();

  const int hw   = blockIdx.x * 1024 + threadIdx.x * 4;
  const int ebhw = b * CHW + hw;
  float acc0[4] = {0.f, 0.f, 0.f, 0.f};
  float acc1[4] = {0.f, 0.f, 0.f, 0.f};

#pragma unroll 1
  for (int u = 0; u < 16; ++u) {
    const int i = 16 * ig + u;
    const float ci = cf[u];
    if (i < k) {
      union { float4 f; __half2 h[4]; } un;
      un.f = *(const float4*)(ts + (size_t)(i * BATCH + b) * HW + hw);
#pragma unroll
      for (int j = 0; j < 4; ++j) {
        float2 v = __half22float2(un.h[j]);
        acc0[j] = fmaf(v.x, ci, acc0[j]);
        acc1[j] = fmaf(v.y, ci, acc1[j]);
      }
    } else {
      const uint32_t kx = kxs[u], ky = kys[u];
#pragma unroll
      for (int j = 0; j < 4; ++j) {
        const uint32_t e = (uint32_t)(ebhw + j);
        uint32_t o0, o1;
        tf2x32(kx, ky, 0u, e,           o0, o1); float t0 = bits_to_normal(o0 ^ o1);
        tf2x32(kx, ky, 0u, e + HW,      o0, o1); float t1 = bits_to_normal(o0 ^ o1);
        tf2x32(kx, ky, 0u, e + 2u * HW, o0, o1); float t2 = bits_to_normal(o0 ^ o1);
        float mu = (t0 + t1 + t2) * (1.0f / 3.0f);
        float d0 = t0 - mu, d1 = t1 - mu, d2 = t2 - mu;
        float var = (d0 * d0 + d1 * d1 + d2 * d2) * 0.5f;
        float g = (SIGMA / sqrtf(var)) * ci;
        acc0[j] = fmaf(d0, g, acc0[j]);
        acc1[j] = fmaf(d1, g, acc1[j]);
      }
    }
  }
#pragma unroll
  for (int j = 0; j < 4; ++j) {
    atomicAdd(out + ebhw + j,           acc0[j]);
    atomicAdd(out + ebhw + HW + j,      acc1[j]);
    atomicAdd(out + ebhw + 2 * HW + j, -(acc0[j] + acc1[j]));
  }
}

extern "C" void kernel_launch(void* const* d_in, const int* in_sizes, int n_in,
                              void* d_out, int out_size, void* d_ws, size_t ws_size,
                              hipStream_t stream) {
  const float* imgs  = (const float*)d_in[0];
  const float* noise = (const float*)d_in[1];
  const float* wv    = (const float*)d_in[2];
  const float* bptr  = (const float*)d_in[3];
  float* out  = (float*)d_out;
  float* dots = (float*)d_ws;
  float* coef = dots + (NUM_IT + 1) * BATCH;
  __half2* ts = (__half2*)(dots + WS_FLOATS);

  // Adaptive staging: stage as many iterations as ws allows (12.85 MB each).
  // ws_size is constant across calls -> same k every launch -> graph-safe.
  size_t avail = ws_size > (size_t)WS_FLOATS * 4 ? ws_size - (size_t)WS_FLOATS * 4 : 0;
  int k = (int)(avail / ((size_t)BATCH * HW * 4));
  if (k > NUM_IT) k = NUM_IT;

  hipMemsetAsync(dots, 0, (NUM_IT + 1) * BATCH * sizeof(float), stream);
  hipMemsetAsync(out, 0, (size_t)out_size * sizeof(float), stream);
  pass1_kernel<<<dim3(49, BATCH, 13), dim3(256), 0, stream>>>(imgs, noise, wv, dots, ts, k);
  coef_kernel<<<dim3(1), dim3(64), 0, stream>>>(dots, bptr, coef);
  pass2_kernel<<<dim3(49, BATCH, 4), dim3(256), 0, stream>>>(out, coef, ts, k);
}

// Round 5
// 2370.110 us; speedup vs baseline: 1.3419x; 1.1082x over previous
//
#include <hip/hip_runtime.h>
#include <stdint.h>

#define NUM_IT 64
#define BATCH 64
#define HW 50176            // 224*224
#define CHW 150528          // 3*HW
#define SIGMA 0.05f

// u12 staging: |s| <= SIGMA*sqrt(2) = 0.07071068 exactly (d_j^2 <= 2*var).
#define QR     0.07071068f
#define QSCALE 28955.082f          // 4095 / (2*QR)
#define QBIAS  2048.0f             // 4095/2 + 0.5 (cvt_u32 truncates)
#define QSTEP  3.45356e-5f         // 2*QR / 4095
// per-(unit,b): 12544 threads * 3 dwords; per unit: 3*12544*4*64 = 9,633,792 B
#define IDX_PER_UB 12544
#define WS_FLOATS ((NUM_IT + 1) * BATCH + BATCH * NUM_IT)   // 8256 floats

// ---------------- Threefry-2x32, 20 rounds (JAX-exact) ----------------
__device__ __forceinline__ void tf2x32(uint32_t k0, uint32_t k1,
                                       uint32_t x0, uint32_t x1,
                                       uint32_t &o0, uint32_t &o1) {
  const uint32_t ks2 = k0 ^ k1 ^ 0x1BD11BDAu;
  x0 += k0; x1 += k1;
#define TF_R(r) { x0 += x1; x1 = __builtin_amdgcn_alignbit(x1, x1, 32u - (r)); x1 ^= x0; }
  TF_R(13) TF_R(15) TF_R(26) TF_R(6)
  x0 += k1;  x1 += ks2 + 1u;
  TF_R(17) TF_R(29) TF_R(16) TF_R(24)
  x0 += ks2; x1 += k0 + 2u;
  TF_R(13) TF_R(15) TF_R(26) TF_R(6)
  x0 += k0;  x1 += k1 + 3u;
  TF_R(17) TF_R(29) TF_R(16) TF_R(24)
  x0 += k1;  x1 += ks2 + 4u;
  TF_R(13) TF_R(15) TF_R(26) TF_R(6)
  x0 += ks2; x1 += k0 + 5u;
#undef TF_R
  o0 = x0; o1 = x1;
}

// bits -> uniform(-0.99999994, 1) -> sqrt(2)*erfinv (XLA/Giles f32 poly).
__device__ __forceinline__ float bits_to_normal(uint32_t bits) {
  const float LO = __uint_as_float(0xBF7FFFFFu);     // nextafter(-1,0)
  float u01 = __uint_as_float((bits >> 9) | 0x3f800000u) - 1.0f;  // [0,1)
  float u = fmaf(u01, 2.0f, LO);
  // 1 - round(u*u) is Sterbenz-exact; __fmul_rn blocks fp-contraction.
  float s = __fmul_rn(u, u);
  float w = -__logf(1.0f - s);
  float p;
  if (w < 5.0f) {
    float z = w - 2.5f;
    p = 2.81022636e-08f;
    p = fmaf(p, z, 3.43273939e-07f);
    p = fmaf(p, z, -3.5233877e-06f);
    p = fmaf(p, z, -4.39150654e-06f);
    p = fmaf(p, z, 0.00021858087f);
    p = fmaf(p, z, -0.00125372503f);
    p = fmaf(p, z, -0.00417768164f);
    p = fmaf(p, z, 0.246640727f);
    p = fmaf(p, z, 1.50140941f);
  } else {
    float z = __builtin_amdgcn_sqrtf(w) - 3.0f;      // fast sqrt: z err ~4e-7
    p = -0.000200214257f;
    p = fmaf(p, z, 0.000100950558f);
    p = fmaf(p, z, 0.00134934322f);
    p = fmaf(p, z, -0.00367342844f);
    p = fmaf(p, z, 0.00573950773f);
    p = fmaf(p, z, -0.0076224613f);
    p = fmaf(p, z, 0.00943887047f);
    p = fmaf(p, z, 1.00167406f);
    p = fmaf(p, z, 2.83297682f);
  }
  return 1.41421356237309515f * (p * u);
}

__device__ __forceinline__ float clip01(float x) {
  return fminf(fmaxf(x, 0.0f), 1.0f);
}

// Pass 1: grid (49, BATCH, 13). Block z=g handles ii-units 5g..5g+4
// (unit 64 == prob2, in group 12). Stages (s0,s1) as packed u12 for unit<k.
__global__ __launch_bounds__(256) void pass1_kernel(
    const float* __restrict__ imgs, const float* __restrict__ noise,
    const float* __restrict__ wv, float* __restrict__ dots,
    uint32_t* __restrict__ ts, const int k)
{
  const int g = blockIdx.z;
  const int b = blockIdx.y;
  __shared__ uint32_t kxs[5], kys[5];
  if (threadIdx.x < 5) {
    const int u = 5 * g + threadIdx.x;
    if (u < NUM_IT) {
      uint32_t kx, ky;
      tf2x32(0u, 42u, 0u, (uint32_t)u, kx, ky);
      kxs[threadIdx.x] = kx; kys[threadIdx.x] = ky;
    }
  }
  __syncthreads();

  const int idx  = blockIdx.x * 256 + threadIdx.x;        // 0..12543
  const int hw   = idx * 4;                               // 4 contiguous elems
  const int ebhw = b * CHW + hw;

  float ba[3][4], wc[3][4];
#pragma unroll
  for (int ch = 0; ch < 3; ++ch) {
    float4 iv = *(const float4*)(imgs  + ebhw + ch * HW);
    float4 nv = *(const float4*)(noise + ebhw + ch * HW);
    float4 wvv = *(const float4*)(wv   + hw   + ch * HW);
    ba[ch][0] = iv.x + nv.x; ba[ch][1] = iv.y + nv.y;
    ba[ch][2] = iv.z + nv.z; ba[ch][3] = iv.w + nv.w;
    wc[ch][0] = wvv.x; wc[ch][1] = wvv.y; wc[ch][2] = wvv.z; wc[ch][3] = wvv.w;
  }

#pragma unroll 1
  for (int u = 0; u < 5; ++u) {
    const int unit = 5 * g + u;       // 0..64; 64 == prob2
    if (unit > NUM_IT) break;
    float sum = 0.0f;
    if (unit == NUM_IT) {
#pragma unroll
      for (int ch = 0; ch < 3; ++ch)
#pragma unroll
        for (int j = 0; j < 4; ++j)
          sum = fmaf(clip01(ba[ch][j]), wc[ch][j], sum);
    } else {
      const uint32_t kx = kxs[u], ky = kys[u];
      uint32_t q[8];
#pragma unroll
      for (int j = 0; j < 4; ++j) {
        const uint32_t e = (uint32_t)(ebhw + j);
        uint32_t o0, o1;
        tf2x32(kx, ky, 0u, e,           o0, o1); float t0 = bits_to_normal(o0 ^ o1);
        tf2x32(kx, ky, 0u, e + HW,      o0, o1); float t1 = bits_to_normal(o0 ^ o1);
        tf2x32(kx, ky, 0u, e + 2u * HW, o0, o1); float t2 = bits_to_normal(o0 ^ o1);
        float mu = (t0 + t1 + t2) * (1.0f / 3.0f);
        float d0 = t0 - mu, d1 = t1 - mu, d2 = t2 - mu;
        float var = (d0 * d0 + d1 * d1 + d2 * d2) * 0.5f;   // ddof=1 over 3
        float sc = SIGMA * __builtin_amdgcn_rsqf(var);      // fast rsq, ~1e-6 rel
        float s0 = d0 * sc, s1 = d1 * sc, s2 = d2 * sc;     // |si| <= QR
        q[2 * j]     = (uint32_t)fmaf(s0, QSCALE, QBIAS);
        q[2 * j + 1] = (uint32_t)fmaf(s1, QSCALE, QBIAS);
        sum = fmaf(clip01(ba[0][j] + s0), wc[0][j], sum);
        sum = fmaf(clip01(ba[1][j] + s1), wc[1][j], sum);
        sum = fmaf(clip01(ba[2][j] + s2), wc[2][j], sum);
      }
      if (unit < k) {
        uint32_t w0 = q[0] | (q[1] << 12) | ((q[2] & 0xFFu) << 24);
        uint32_t w1 = (q[2] >> 8) | (q[3] << 4) | (q[4] << 16) | ((q[5] & 0xFu) << 28);
        uint32_t w2 = (q[5] >> 4) | (q[6] << 8) | (q[7] << 20);
        uint32_t* p = ts + ((size_t)(unit * BATCH + b) * 3) * IDX_PER_UB + idx;
        p[0] = w0; p[IDX_PER_UB] = w1; p[2 * IDX_PER_UB] = w2;
      }
    }
    for (int off = 32; off; off >>= 1) sum += __shfl_down(sum, off, 64);
    if ((threadIdx.x & 63) == 0) atomicAdd(&dots[unit * BATCH + b], sum);
  }
}

__global__ void coef_kernel(const float* __restrict__ dots,
                            const float* __restrict__ bptr,
                            float* __restrict__ coef) {
  const int b = threadIdx.x;  // 64 threads
  const float bias = bptr[0];
  const float p2 = 1.0f / (1.0f + expf(-(dots[NUM_IT * BATCH + b] + bias)));
  float nc = 0.0f;
  for (int i = 0; i < NUM_IT; ++i) {
    float ap = 1.0f / (1.0f + expf(-(dots[i * BATCH + b] + bias)));
    float d = p2 - ap;
    nc += d * d;
  }
  const float inv = 1.0f / ((float)NUM_IT * SIGMA * (sqrtf(nc) + 1e-10f));
  for (int i = 0; i < NUM_IT; ++i) {
    float ap = 1.0f / (1.0f + expf(-(dots[i * BATCH + b] + bias)));
    float d = p2 - ap;
    coef[b * NUM_IT + i] = d * inv;
  }
}

// Pass 2: grid (49, BATCH, 4). Block z=ig handles i = 16*ig..16*ig+15;
// partials atomically added into zero-initialized out. i<k streams staged
// u12; i>=k regenerates. ch2 = -(ch0+ch1).
__global__ __launch_bounds__(256) void pass2_kernel(
    float* __restrict__ out, const float* __restrict__ coef,
    const uint32_t* __restrict__ ts, const int k)
{
  const int ig = blockIdx.z;
  const int b  = blockIdx.y;
  __shared__ float cf[16];
  __shared__ uint32_t kxs[16], kys[16];
  if (threadIdx.x < 16) {
    const int i = 16 * ig + threadIdx.x;
    cf[threadIdx.x] = coef[b * NUM_IT + i];
    if (i >= k) {
      uint32_t kx, ky;
      tf2x32(0u, 42u, 0u, (uint32_t)i, kx, ky);
      kxs[threadIdx.x] = kx; kys[threadIdx.x] = ky;
    }
  }
  __syncthreads();

  const int idx  = blockIdx.x * 256 + threadIdx.x;
  const int hw   = idx * 4;
  const int ebhw = b * CHW + hw;
  float acc0[4] = {0.f, 0.f, 0.f, 0.f};
  float acc1[4] = {0.f, 0.f, 0.f, 0.f};

#pragma unroll 1
  for (int u = 0; u < 16; ++u) {
    const int i = 16 * ig + u;
    const float ci = cf[u];
    if (i < k) {
      const uint32_t* p = ts + ((size_t)(i * BATCH + b) * 3) * IDX_PER_UB + idx;
      uint32_t w0 = p[0], w1 = p[IDX_PER_UB], w2 = p[2 * IDX_PER_UB];
      uint32_t q[8];
      q[0] = w0 & 0xFFFu;
      q[1] = (w0 >> 12) & 0xFFFu;
      q[2] = (w0 >> 24) | ((w1 & 0xFu) << 8);
      q[3] = (w1 >> 4) & 0xFFFu;
      q[4] = (w1 >> 16) & 0xFFFu;
      q[5] = (w1 >> 28) | ((w2 & 0xFFu) << 4);
      q[6] = (w2 >> 8) & 0xFFFu;
      q[7] = w2 >> 20;
#pragma unroll
      for (int j = 0; j < 4; ++j) {
        float s0 = fmaf((float)q[2 * j],     QSTEP, -QR);
        float s1 = fmaf((float)q[2 * j + 1], QSTEP, -QR);
        acc0[j] = fmaf(s0, ci, acc0[j]);
        acc1[j] = fmaf(s1, ci, acc1[j]);
      }
    } else {
      const uint32_t kx = kxs[u], ky = kys[u];
#pragma unroll
      for (int j = 0; j < 4; ++j) {
        const uint32_t e = (uint32_t)(ebhw + j);
        uint32_t o0, o1;
        tf2x32(kx, ky, 0u, e,           o0, o1); float t0 = bits_to_normal(o0 ^ o1);
        tf2x32(kx, ky, 0u, e + HW,      o0, o1); float t1 = bits_to_normal(o0 ^ o1);
        tf2x32(kx, ky, 0u, e + 2u * HW, o0, o1); float t2 = bits_to_normal(o0 ^ o1);
        float mu = (t0 + t1 + t2) * (1.0f / 3.0f);
        float d0 = t0 - mu, d1 = t1 - mu, d2 = t2 - mu;
        float var = (d0 * d0 + d1 * d1 + d2 * d2) * 0.5f;
        float gg = (SIGMA * __builtin_amdgcn_rsqf(var)) * ci;
        acc0[j] = fmaf(d0, gg, acc0[j]);
        acc1[j] = fmaf(d1, gg, acc1[j]);
      }
    }
  }
#pragma unroll
  for (int j = 0; j < 4; ++j) {
    atomicAdd(out + ebhw + j,           acc0[j]);
    atomicAdd(out + ebhw + HW + j,      acc1[j]);
    atomicAdd(out + ebhw + 2 * HW + j, -(acc0[j] + acc1[j]));
  }
}

extern "C" void kernel_launch(void* const* d_in, const int* in_sizes, int n_in,
                              void* d_out, int out_size, void* d_ws, size_t ws_size,
                              hipStream_t stream) {
  const float* imgs  = (const float*)d_in[0];
  const float* noise = (const float*)d_in[1];
  const float* wv    = (const float*)d_in[2];
  const float* bptr  = (const float*)d_in[3];
  float* out  = (float*)d_out;
  float* dots = (float*)d_ws;
  float* coef = dots + (NUM_IT + 1) * BATCH;
  uint32_t* ts = (uint32_t*)(dots + WS_FLOATS);

  // Adaptive staging: 9,633,792 B per staged iteration (u12-packed pairs).
  // ws_size is constant across calls -> same k every launch -> graph-safe.
  size_t avail = ws_size > (size_t)WS_FLOATS * 4 ? ws_size - (size_t)WS_FLOATS * 4 : 0;
  int k = (int)(avail / ((size_t)IDX_PER_UB * 3 * 4 * BATCH));
  if (k > NUM_IT) k = NUM_IT;

  hipMemsetAsync(dots, 0, (NUM_IT + 1) * BATCH * sizeof(float), stream);
  hipMemsetAsync(out, 0, (size_t)out_size * sizeof(float), stream);
  pass1_kernel<<<dim3(49, BATCH, 13), dim3(256), 0, stream>>>(imgs, noise, wv, dots, ts, k);
  coef_kernel<<<dim3(1), dim3(64), 0, stream>>>(dots, bptr, coef);
  pass2_kernel<<<dim3(49, BATCH, 4), dim3(256), 0, stream>>>(out, coef, ts, k);
}

// Round 6
// 2008.343 us; speedup vs baseline: 1.5836x; 1.1801x over previous
//
#include <hip/hip_runtime.h>
#include <stdint.h>

#define NUM_IT 64
#define BATCH 64
#define HW 50176            // 224*224
#define CHW 150528          // 3*HW
#define SIGMA 0.05f

// u8 staging. True range: |s| <= SIGMA*2/sqrt(3) (3 zero-sum values ->
// max |d_j|/sqrt(var) = 2/sqrt(3)), NOT sigma*sqrt(2).
#define QR8       0.057735027f
#define ENC_SCALE 2208.3655f        // 255 / (2*QR8)
#define ENC_BIAS  127.5f            // s=0 -> q=127 (cvt_u32 truncates)
#define DEC_STEP  4.52824e-4f       // 2*QR8 / 255
#define DEC_BIAS  (-0.057508615f)   // step/2 - QR8 (midpoint decode, unbiased)
// per-(unit,b): 12544 threads * uint2; per unit: 12544*8*64 = 6,422,528 B
#define IDX_PER_UB 12544
#define WS_FLOATS ((NUM_IT + 1) * BATCH + BATCH * NUM_IT)   // 8256 floats

// ---------------- Threefry-2x32, 20 rounds (JAX-exact) ----------------
__device__ __forceinline__ void tf2x32(uint32_t k0, uint32_t k1,
                                       uint32_t x0, uint32_t x1,
                                       uint32_t &o0, uint32_t &o1) {
  const uint32_t ks2 = k0 ^ k1 ^ 0x1BD11BDAu;
  x0 += k0; x1 += k1;
#define TF_R(r) { x0 += x1; x1 = __builtin_amdgcn_alignbit(x1, x1, 32u - (r)); x1 ^= x0; }
  TF_R(13) TF_R(15) TF_R(26) TF_R(6)
  x0 += k1;  x1 += ks2 + 1u;
  TF_R(17) TF_R(29) TF_R(16) TF_R(24)
  x0 += ks2; x1 += k0 + 2u;
  TF_R(13) TF_R(15) TF_R(26) TF_R(6)
  x0 += k0;  x1 += k1 + 3u;
  TF_R(17) TF_R(29) TF_R(16) TF_R(24)
  x0 += k1;  x1 += ks2 + 4u;
  TF_R(13) TF_R(15) TF_R(26) TF_R(6)
  x0 += ks2; x1 += k0 + 5u;
#undef TF_R
  o0 = x0; o1 = x1;
}

// bits -> uniform(-0.99999994, 1) -> sqrt(2)*erfinv (XLA/Giles f32 poly).
__device__ __forceinline__ float bits_to_normal(uint32_t bits) {
  const float LO = __uint_as_float(0xBF7FFFFFu);     // nextafter(-1,0)
  float u01 = __uint_as_float((bits >> 9) | 0x3f800000u) - 1.0f;  // [0,1)
  float u = fmaf(u01, 2.0f, LO);
  // 1 - round(u*u) is Sterbenz-exact; __fmul_rn blocks fp-contraction.
  float s = __fmul_rn(u, u);
  float w = -__logf(1.0f - s);
  float p;
  if (w < 5.0f) {
    float z = w - 2.5f;
    p = 2.81022636e-08f;
    p = fmaf(p, z, 3.43273939e-07f);
    p = fmaf(p, z, -3.5233877e-06f);
    p = fmaf(p, z, -4.39150654e-06f);
    p = fmaf(p, z, 0.00021858087f);
    p = fmaf(p, z, -0.00125372503f);
    p = fmaf(p, z, -0.00417768164f);
    p = fmaf(p, z, 0.246640727f);
    p = fmaf(p, z, 1.50140941f);
  } else {
    float z = __builtin_amdgcn_sqrtf(w) - 3.0f;      // fast sqrt: z err ~4e-7
    p = -0.000200214257f;
    p = fmaf(p, z, 0.000100950558f);
    p = fmaf(p, z, 0.00134934322f);
    p = fmaf(p, z, -0.00367342844f);
    p = fmaf(p, z, 0.00573950773f);
    p = fmaf(p, z, -0.0076224613f);
    p = fmaf(p, z, 0.00943887047f);
    p = fmaf(p, z, 1.00167406f);
    p = fmaf(p, z, 2.83297682f);
  }
  return 1.41421356237309515f * (p * u);
}

__device__ __forceinline__ float clip01(float x) {
  return fminf(fmaxf(x, 0.0f), 1.0f);
}

// Pass 1: grid (49, BATCH, 13). Block z=g handles ii-units 5g..5g+4
// (unit 64 == prob2, in group 12). Stages (s0,s1) as u8 pairs for unit<k.
__global__ __launch_bounds__(256) void pass1_kernel(
    const float* __restrict__ imgs, const float* __restrict__ noise,
    const float* __restrict__ wv, float* __restrict__ dots,
    uint2* __restrict__ ts, const int k)
{
  const int g = blockIdx.z;
  const int b = blockIdx.y;
  __shared__ uint32_t kxs[5], kys[5];
  if (threadIdx.x < 5) {
    const int u = 5 * g + threadIdx.x;
    if (u < NUM_IT) {
      uint32_t kx, ky;
      tf2x32(0u, 42u, 0u, (uint32_t)u, kx, ky);
      kxs[threadIdx.x] = kx; kys[threadIdx.x] = ky;
    }
  }
  __syncthreads();

  const int idx  = blockIdx.x * 256 + threadIdx.x;        // 0..12543
  const int hw   = idx * 4;                               // 4 contiguous elems
  const int ebhw = b * CHW + hw;

  float ba[3][4], wc[3][4];
#pragma unroll
  for (int ch = 0; ch < 3; ++ch) {
    float4 iv = *(const float4*)(imgs  + ebhw + ch * HW);
    float4 nv = *(const float4*)(noise + ebhw + ch * HW);
    float4 wvv = *(const float4*)(wv   + hw   + ch * HW);
    ba[ch][0] = iv.x + nv.x; ba[ch][1] = iv.y + nv.y;
    ba[ch][2] = iv.z + nv.z; ba[ch][3] = iv.w + nv.w;
    wc[ch][0] = wvv.x; wc[ch][1] = wvv.y; wc[ch][2] = wvv.z; wc[ch][3] = wvv.w;
  }

#pragma unroll 1
  for (int u = 0; u < 5; ++u) {
    const int unit = 5 * g + u;       // 0..64; 64 == prob2
    if (unit > NUM_IT) break;
    float sum = 0.0f;
    if (unit == NUM_IT) {
#pragma unroll
      for (int ch = 0; ch < 3; ++ch)
#pragma unroll
        for (int j = 0; j < 4; ++j)
          sum = fmaf(clip01(ba[ch][j]), wc[ch][j], sum);
    } else {
      const uint32_t kx = kxs[u], ky = kys[u];
      uint32_t qa = 0, qb = 0;
#pragma unroll
      for (int j = 0; j < 4; ++j) {
        const uint32_t e = (uint32_t)(ebhw + j);
        uint32_t o0, o1;
        tf2x32(kx, ky, 0u, e,           o0, o1); float t0 = bits_to_normal(o0 ^ o1);
        tf2x32(kx, ky, 0u, e + HW,      o0, o1); float t1 = bits_to_normal(o0 ^ o1);
        tf2x32(kx, ky, 0u, e + 2u * HW, o0, o1); float t2 = bits_to_normal(o0 ^ o1);
        float mu = (t0 + t1 + t2) * (1.0f / 3.0f);
        float d0 = t0 - mu, d1 = t1 - mu, d2 = t2 - mu;
        float var = (d0 * d0 + d1 * d1 + d2 * d2) * 0.5f;   // ddof=1 over 3
        float sc = SIGMA * __builtin_amdgcn_rsqf(var);      // fast rsq, ~1e-6 rel
        float s0 = d0 * sc, s1 = d1 * sc, s2 = d2 * sc;     // |si| <= QR8
        qa |= ((uint32_t)fmaf(s0, ENC_SCALE, ENC_BIAS)) << (8 * j);
        qb |= ((uint32_t)fmaf(s1, ENC_SCALE, ENC_BIAS)) << (8 * j);
        sum = fmaf(clip01(ba[0][j] + s0), wc[0][j], sum);
        sum = fmaf(clip01(ba[1][j] + s1), wc[1][j], sum);
        sum = fmaf(clip01(ba[2][j] + s2), wc[2][j], sum);
      }
      if (unit < k) {
        uint2 w; w.x = qa; w.y = qb;
        ts[(size_t)(unit * BATCH + b) * IDX_PER_UB + idx] = w;
      }
    }
    for (int off = 32; off; off >>= 1) sum += __shfl_down(sum, off, 64);
    if ((threadIdx.x & 63) == 0) atomicAdd(&dots[unit * BATCH + b], sum);
  }
}

__global__ void coef_kernel(const float* __restrict__ dots,
                            const float* __restrict__ bptr,
                            float* __restrict__ coef) {
  const int b = threadIdx.x;  // 64 threads
  const float bias = bptr[0];
  const float p2 = 1.0f / (1.0f + expf(-(dots[NUM_IT * BATCH + b] + bias)));
  float nc = 0.0f;
  for (int i = 0; i < NUM_IT; ++i) {
    float ap = 1.0f / (1.0f + expf(-(dots[i * BATCH + b] + bias)));
    float d = p2 - ap;
    nc += d * d;
  }
  const float inv = 1.0f / ((float)NUM_IT * SIGMA * (sqrtf(nc) + 1e-10f));
  for (int i = 0; i < NUM_IT; ++i) {
    float ap = 1.0f / (1.0f + expf(-(dots[i * BATCH + b] + bias)));
    float d = p2 - ap;
    coef[b * NUM_IT + i] = d * inv;
  }
}

// Pass 2: grid (49, BATCH, 4). Group z handles units i == 4u+z (u=0..15) so
// regen units (i>=k) spread evenly across groups. Partials atomically added
// into zero-initialized out. ch2 = -(ch0+ch1).
__global__ __launch_bounds__(256) void pass2_kernel(
    float* __restrict__ out, const float* __restrict__ coef,
    const uint2* __restrict__ ts, const int k)
{
  const int z = blockIdx.z;
  const int b = blockIdx.y;
  __shared__ float cf[16];
  __shared__ uint32_t kxs[16], kys[16];
  if (threadIdx.x < 16) {
    const int i = 4 * threadIdx.x + z;
    cf[threadIdx.x] = coef[b * NUM_IT + i];
    if (i >= k) {
      uint32_t kx, ky;
      tf2x32(0u, 42u, 0u, (uint32_t)i, kx, ky);
      kxs[threadIdx.x] = kx; kys[threadIdx.x] = ky;
    }
  }
  __syncthreads();

  const int idx  = blockIdx.x * 256 + threadIdx.x;
  const int hw   = idx * 4;
  const int ebhw = b * CHW + hw;
  float acc0[4] = {0.f, 0.f, 0.f, 0.f};
  float acc1[4] = {0.f, 0.f, 0.f, 0.f};

#pragma unroll 1
  for (int u = 0; u < 16; ++u) {
    const int i = 4 * u + z;
    const float ci = cf[u];
    if (i < k) {
      uint2 w = ts[(size_t)(i * BATCH + b) * IDX_PER_UB + idx];
#pragma unroll
      for (int j = 0; j < 4; ++j) {
        float s0 = fmaf((float)((w.x >> (8 * j)) & 0xFFu), DEC_STEP, DEC_BIAS);
        float s1 = fmaf((float)((w.y >> (8 * j)) & 0xFFu), DEC_STEP, DEC_BIAS);
        acc0[j] = fmaf(s0, ci, acc0[j]);
        acc1[j] = fmaf(s1, ci, acc1[j]);
      }
    } else {
      const uint32_t kx = kxs[u], ky = kys[u];
#pragma unroll
      for (int j = 0; j < 4; ++j) {
        const uint32_t e = (uint32_t)(ebhw + j);
        uint32_t o0, o1;
        tf2x32(kx, ky, 0u, e,           o0, o1); float t0 = bits_to_normal(o0 ^ o1);
        tf2x32(kx, ky, 0u, e + HW,      o0, o1); float t1 = bits_to_normal(o0 ^ o1);
        tf2x32(kx, ky, 0u, e + 2u * HW, o0, o1); float t2 = bits_to_normal(o0 ^ o1);
        float mu = (t0 + t1 + t2) * (1.0f / 3.0f);
        float d0 = t0 - mu, d1 = t1 - mu, d2 = t2 - mu;
        float var = (d0 * d0 + d1 * d1 + d2 * d2) * 0.5f;
        float gg = (SIGMA * __builtin_amdgcn_rsqf(var)) * ci;
        acc0[j] = fmaf(d0, gg, acc0[j]);
        acc1[j] = fmaf(d1, gg, acc1[j]);
      }
    }
  }
#pragma unroll
  for (int j = 0; j < 4; ++j) {
    atomicAdd(out + ebhw + j,           acc0[j]);
    atomicAdd(out + ebhw + HW + j,      acc1[j]);
    atomicAdd(out + ebhw + 2 * HW + j, -(acc0[j] + acc1[j]));
  }
}

extern "C" void kernel_launch(void* const* d_in, const int* in_sizes, int n_in,
                              void* d_out, int out_size, void* d_ws, size_t ws_size,
                              hipStream_t stream) {
  const float* imgs  = (const float*)d_in[0];
  const float* noise = (const float*)d_in[1];
  const float* wv    = (const float*)d_in[2];
  const float* bptr  = (const float*)d_in[3];
  float* out  = (float*)d_out;
  float* dots = (float*)d_ws;
  float* coef = dots + (NUM_IT + 1) * BATCH;
  uint2* ts = (uint2*)(dots + WS_FLOATS);

  // Adaptive staging: 6,422,528 B per staged iteration (u8 pairs).
  // ws_size is constant across calls -> same k every launch -> graph-safe.
  size_t avail = ws_size > (size_t)WS_FLOATS * 4 ? ws_size - (size_t)WS_FLOATS * 4 : 0;
  int k = (int)(avail / ((size_t)IDX_PER_UB * 8 * BATCH));
  if (k > NUM_IT) k = NUM_IT;

  hipMemsetAsync(dots, 0, (NUM_IT + 1) * BATCH * sizeof(float), stream);
  hipMemsetAsync(out, 0, (size_t)out_size * sizeof(float), stream);
  pass1_kernel<<<dim3(49, BATCH, 13), dim3(256), 0, stream>>>(imgs, noise, wv, dots, ts, k);
  coef_kernel<<<dim3(1), dim3(64), 0, stream>>>(dots, bptr, coef);
  pass2_kernel<<<dim3(49, BATCH, 4), dim3(256), 0, stream>>>(out, coef, ts, k);
}